// Round 1
// baseline (797.636 us; speedup 1.0000x reference)
//
#include <hip/hip_runtime.h>
#include <math.h>

// Problem constants (fixed by reference: B=8, C=3, H=W=1024)
constexpr int BC = 24;     // B*C point-set pairs
constexpr int N  = 1024;   // points per set (rows)
constexpr int D  = 1024;   // point dimension (cols)
constexpr int TILE = 128;  // output tile (128x128 per block)
constexpr int BK = 16;     // K-tile
constexpr int LDA = 132;   // padded LDS leading dim (132*4B: keeps float4 align, kills write conflicts)

#define FINF 3.402823466e+38f

// ---- Kernel 1: row norms ||x_n||^2 for both tensors ----
__global__ __launch_bounds__(256) void norms_kernel(const float* __restrict__ X,
                                                    const float* __restrict__ Y,
                                                    float* __restrict__ xn,
                                                    float* __restrict__ yn) {
    int rid = blockIdx.x;                 // 0 .. 2*BC*N-1
    bool isY = rid >= BC * N;
    int row = isY ? rid - BC * N : rid;
    const float* src = (isY ? Y : X) + (size_t)row * D;
    float4 v = ((const float4*)src)[threadIdx.x];     // 256 threads * 4 = 1024 elems
    float s = v.x * v.x + v.y * v.y + v.z * v.z + v.w * v.w;
    #pragma unroll
    for (int m = 1; m < 64; m <<= 1) s += __shfl_xor(s, m, 64);
    __shared__ float ws[4];
    int lane = threadIdx.x & 63, w = threadIdx.x >> 6;
    if (lane == 0) ws[w] = s;
    __syncthreads();
    if (threadIdx.x == 0) (isY ? yn : xn)[row] = ws[0] + ws[1] + ws[2] + ws[3];
}

// ---- Kernel 2: tiled "GEMM" + on-the-fly min reductions on clamped d2 ----
__global__ __launch_bounds__(256) void tile_kernel(const float* __restrict__ X,
                                                   const float* __restrict__ Y,
                                                   const float* __restrict__ xn,
                                                   const float* __restrict__ yn,
                                                   unsigned* __restrict__ rowmin,
                                                   unsigned* __restrict__ colmin) {
    __shared__ float As[BK][LDA];   // transposed: As[k][n]
    __shared__ float Bs[BK][LDA];   // transposed: Bs[k][m]
    int bc = blockIdx.z, tn = blockIdx.y, tm = blockIdx.x;
    const float* Xb = X + (size_t)bc * N * D + (size_t)tn * TILE * D;
    const float* Yb = Y + (size_t)bc * N * D + (size_t)tm * TILE * D;
    int t = threadIdx.x;
    int tx = t & 15, ty = t >> 4;   // 16x16 thread grid; thread owns 8 rows x 8 cols

    float acc[8][8];
    #pragma unroll
    for (int i = 0; i < 8; i++)
        #pragma unroll
        for (int j = 0; j < 8; j++) acc[i][j] = 0.f;

    for (int k0 = 0; k0 < D; k0 += BK) {
        // Stage 128x16 tiles of X and Y, transposed into LDS.
        #pragma unroll
        for (int i = 0; i < 2; i++) {
            int c = t + i * 256;        // 512 chunks of 4 floats
            int r = c >> 2;             // row 0..127
            int kk = (c & 3) * 4;       // k offset 0,4,8,12
            float4 v = *(const float4*)(Xb + (size_t)r * D + k0 + kk);
            As[kk + 0][r] = v.x; As[kk + 1][r] = v.y; As[kk + 2][r] = v.z; As[kk + 3][r] = v.w;
            float4 w = *(const float4*)(Yb + (size_t)r * D + k0 + kk);
            Bs[kk + 0][r] = w.x; Bs[kk + 1][r] = w.y; Bs[kk + 2][r] = w.z; Bs[kk + 3][r] = w.w;
        }
        __syncthreads();
        #pragma unroll
        for (int k = 0; k < BK; k++) {
            float a[8], b[8];
            *(float4*)&a[0] = *(const float4*)&As[k][ty * 8];
            *(float4*)&a[4] = *(const float4*)&As[k][ty * 8 + 4];
            *(float4*)&b[0] = *(const float4*)&Bs[k][tx * 8];
            *(float4*)&b[4] = *(const float4*)&Bs[k][tx * 8 + 4];
            #pragma unroll
            for (int i = 0; i < 8; i++)
                #pragma unroll
                for (int j = 0; j < 8; j++) acc[i][j] = fmaf(a[i], b[j], acc[i][j]);
        }
        __syncthreads();
    }

    // Epilogue: d2 = clamp(x2 + y2 - 2*xy, 0); track per-row and per-col mins.
    float xnr[8], ynr[8];
    #pragma unroll
    for (int i = 0; i < 8; i++) xnr[i] = xn[bc * N + tn * TILE + ty * 8 + i];
    #pragma unroll
    for (int j = 0; j < 8; j++) ynr[j] = yn[bc * N + tm * TILE + tx * 8 + j];

    float rmin[8], cmin[8];
    #pragma unroll
    for (int i = 0; i < 8; i++) { rmin[i] = FINF; cmin[i] = FINF; }
    #pragma unroll
    for (int i = 0; i < 8; i++)
        #pragma unroll
        for (int j = 0; j < 8; j++) {
            float d2 = fmaxf(xnr[i] + ynr[j] - 2.f * acc[i][j], 0.f);
            rmin[i] = fminf(rmin[i], d2);
            cmin[j] = fminf(cmin[j], d2);
        }

    // Row mins: reduce across tx (16 consecutive lanes share ty).
    #pragma unroll
    for (int m = 1; m < 16; m <<= 1)
        #pragma unroll
        for (int i = 0; i < 8; i++) rmin[i] = fminf(rmin[i], __shfl_xor(rmin[i], m, 64));
    if (tx == 0) {
        #pragma unroll
        for (int i = 0; i < 8; i++)
            atomicMin(&rowmin[bc * N + tn * TILE + ty * 8 + i], __float_as_uint(rmin[i]));
    }

    // Col mins: reduce across ty (cross-wave) via LDS (reuse As storage).
    __syncthreads();
    float* scol = &As[0][0];            // need 16*128 = 2048 floats; As has 16*132
    #pragma unroll
    for (int j = 0; j < 8; j++) scol[ty * TILE + tx * 8 + j] = cmin[j];
    __syncthreads();
    if (t < TILE) {
        float v = scol[t];
        #pragma unroll
        for (int i = 1; i < 16; i++) v = fminf(v, scol[i * TILE + t]);
        atomicMin(&colmin[bc * N + tm * TILE + t], __float_as_uint(v));
    }
}

// ---- Kernel 3: per-bc max over row/col mins, sqrt, mean over bc ----
__global__ __launch_bounds__(256) void finalize_kernel(const unsigned* __restrict__ rowmin,
                                                       const unsigned* __restrict__ colmin,
                                                       float* __restrict__ out) {
    int bc = blockIdx.x;
    float v = 0.f;   // d2 >= 0, so 0 is a valid identity for max
    for (int i = threadIdx.x; i < N; i += 256) {
        v = fmaxf(v, __uint_as_float(rowmin[bc * N + i]));
        v = fmaxf(v, __uint_as_float(colmin[bc * N + i]));
    }
    #pragma unroll
    for (int m = 1; m < 64; m <<= 1) v = fmaxf(v, __shfl_xor(v, m, 64));
    __shared__ float ws[4];
    int lane = threadIdx.x & 63, w = threadIdx.x >> 6;
    if (lane == 0) ws[w] = v;
    __syncthreads();
    if (threadIdx.x == 0) {
        float m = fmaxf(fmaxf(ws[0], ws[1]), fmaxf(ws[2], ws[3]));
        atomicAdd(out, sqrtf(m) * (1.0f / (float)BC));
    }
}

extern "C" void kernel_launch(void* const* d_in, const int* in_sizes, int n_in,
                              void* d_out, int out_size, void* d_ws, size_t ws_size,
                              hipStream_t stream) {
    const float* X = (const float*)d_in[0];   // input  [8,3,1024,1024]
    const float* Y = (const float*)d_in[1];   // target [8,3,1024,1024]
    float* out = (float*)d_out;               // scalar

    // Workspace layout (floats): rowmin[24*1024] | colmin[24*1024] | xn[24*1024] | yn[24*1024]
    unsigned* rowmin = (unsigned*)d_ws;
    unsigned* colmin = rowmin + BC * N;
    float* xn = (float*)(colmin + BC * N);
    float* yn = xn + BC * N;

    // 0xFFFFFFFF == UINT_MAX: identity for uint atomicMin on non-negative float bit patterns.
    hipMemsetAsync(d_ws, 0xFF, (size_t)2 * BC * N * sizeof(unsigned), stream);
    hipMemsetAsync(d_out, 0, sizeof(float), stream);

    norms_kernel<<<2 * BC * N, 256, 0, stream>>>(X, Y, xn, yn);

    dim3 grid(N / TILE, N / TILE, BC);  // (tm, tn, bc) = (8, 8, 24)
    tile_kernel<<<grid, 256, 0, stream>>>(X, Y, xn, yn, rowmin, colmin);

    finalize_kernel<<<BC, 256, 0, stream>>>(rowmin, colmin, out);
}

// Round 2
// 339.902 us; speedup vs baseline: 2.3467x; 2.3467x over previous
//
#include <hip/hip_runtime.h>
#include <math.h>

// Problem constants (fixed by reference: B=8, C=3, H=W=1024)
constexpr int BC = 24;     // B*C point-set pairs
constexpr int N  = 1024;   // points per set
constexpr int D  = 1024;   // point dimension
constexpr int TILE = 128;  // 128x128 output tile per block
constexpr int BK = 32;     // K-slab (one 16x16x32 MFMA dose)
constexpr int SK = BK + 8; // padded LDS stride in bf16 elems (80 B = 16B-aligned)

typedef short short8 __attribute__((ext_vector_type(8)));
typedef float f32x4  __attribute__((ext_vector_type(4)));

#define FINF 3.402823466e+38f

// Pack two fp32 -> two bf16 (round-half-up via +0x8000, then take hi16).
// result: low16 = bf16(a), high16 = bf16(b). 3 VALU ops for 2 elements.
__device__ inline unsigned pk_bf16(float a, float b) {
    unsigned ua = __float_as_uint(a) + 0x8000u;
    unsigned ub = __float_as_uint(b) + 0x8000u;
    // perm(src0=ub, src1=ua): byte sel 0..3 = ua bytes, 4..7 = ub bytes
    return __builtin_amdgcn_perm(ub, ua, 0x07060302);
}

// ---- Kernel 1: row norms ||p||^2 for both tensors (one wave per row) ----
__global__ __launch_bounds__(256) void norms_kernel(const float* __restrict__ X,
                                                    const float* __restrict__ Y,
                                                    float* __restrict__ xn,
                                                    float* __restrict__ yn) {
    int w = threadIdx.x >> 6, lane = threadIdx.x & 63;
    long rid = (long)blockIdx.x * 4 + w;          // 0 .. 2*BC*N-1
    bool isY = rid >= (long)BC * N;
    long row = isY ? rid - (long)BC * N : rid;
    const float* src = (isY ? Y : X) + row * D;
    float s = 0.f;
    #pragma unroll
    for (int q = 0; q < 4; q++) {
        float4 v = ((const float4*)src)[lane + q * 64];
        s += v.x * v.x + v.y * v.y + v.z * v.z + v.w * v.w;
    }
    #pragma unroll
    for (int m = 1; m < 64; m <<= 1) s += __shfl_xor(s, m, 64);
    if (lane == 0) (isY ? yn : xn)[row] = s;
}

// ---- Kernel 2: bf16 MFMA tile kernel + on-the-fly min reductions ----
__global__ __launch_bounds__(256) void tile_kernel(const float* __restrict__ X,
                                                   const float* __restrict__ Y,
                                                   const float* __restrict__ xn,
                                                   const float* __restrict__ yn,
                                                   unsigned* __restrict__ rowmin,
                                                   unsigned* __restrict__ colmin) {
    __shared__ unsigned short Xs[TILE * SK];   // Xs[row][k], stride SK
    __shared__ unsigned short Ys[TILE * SK];
    int bc = blockIdx.z, tn = blockIdx.y, tm = blockIdx.x;
    const float* Xb = X + ((size_t)bc * N + (size_t)tn * TILE) * D;
    const float* Yb = Y + ((size_t)bc * N + (size_t)tm * TILE) * D;

    int t = threadIdx.x;
    int srow = t >> 3;            // staging row 0..31 (+i*32)
    int sq   = t & 7;             // float4 index within 32-float K-slab
    int wave = t >> 6, lane = t & 63;
    int wr = wave >> 1, wc = wave & 1;      // wave tile: rows wr*64, cols wc*64
    int quad = lane >> 4, tx = lane & 15;

    f32x4 acc[4][4];
    #pragma unroll
    for (int i = 0; i < 4; i++)
        #pragma unroll
        for (int j = 0; j < 4; j++) acc[i][j] = (f32x4)0.f;

    // Register prefetch of the first K-slab.
    float4 xv[4], yv[4];
    #pragma unroll
    for (int i = 0; i < 4; i++) {
        xv[i] = *(const float4*)(Xb + (size_t)(srow + i * 32) * D + sq * 4);
        yv[i] = *(const float4*)(Yb + (size_t)(srow + i * 32) * D + sq * 4);
    }

    for (int k0 = 0; k0 < D; k0 += BK) {
        __syncthreads();   // previous iter's LDS reads complete
        #pragma unroll
        for (int i = 0; i < 4; i++) {
            uint2 px; px.x = pk_bf16(xv[i].x, xv[i].y); px.y = pk_bf16(xv[i].z, xv[i].w);
            *(uint2*)&Xs[(srow + i * 32) * SK + sq * 4] = px;
            uint2 py; py.x = pk_bf16(yv[i].x, yv[i].y); py.y = pk_bf16(yv[i].z, yv[i].w);
            *(uint2*)&Ys[(srow + i * 32) * SK + sq * 4] = py;
        }
        __syncthreads();
        if (k0 + BK < D) {   // prefetch next slab while MFMA runs
            #pragma unroll
            for (int i = 0; i < 4; i++) {
                xv[i] = *(const float4*)(Xb + (size_t)(srow + i * 32) * D + k0 + BK + sq * 4);
                yv[i] = *(const float4*)(Yb + (size_t)(srow + i * 32) * D + k0 + BK + sq * 4);
            }
        }
        // A-frag: lane holds A[m = tx][k = quad*8 + j]; B-frag mirrors with n = tx.
        short8 af[4], bg[4];
        #pragma unroll
        for (int mi = 0; mi < 4; mi++)
            af[mi] = *(const short8*)&Xs[(wr * 64 + mi * 16 + tx) * SK + quad * 8];
        #pragma unroll
        for (int mj = 0; mj < 4; mj++)
            bg[mj] = *(const short8*)&Ys[(wc * 64 + mj * 16 + tx) * SK + quad * 8];
        #pragma unroll
        for (int mi = 0; mi < 4; mi++)
            #pragma unroll
            for (int mj = 0; mj < 4; mj++)
                acc[mi][mj] = __builtin_amdgcn_mfma_f32_16x16x32_bf16(af[mi], bg[mj], acc[mi][mj], 0, 0, 0);
    }

    // Epilogue. D-layout: row = quad*4 + r (X row), col = tx (Y row) within each 16x16 tile.
    int rbase = bc * N + tn * TILE + wr * 64;
    int cbase = bc * N + tm * TILE + wc * 64;
    float xnr[4][4], ynr[4];
    #pragma unroll
    for (int mi = 0; mi < 4; mi++)
        #pragma unroll
        for (int r = 0; r < 4; r++) xnr[mi][r] = xn[rbase + mi * 16 + quad * 4 + r];
    #pragma unroll
    for (int mj = 0; mj < 4; mj++) ynr[mj] = yn[cbase + mj * 16 + tx];

    float rmin[4][4], cmin[4];
    #pragma unroll
    for (int mi = 0; mi < 4; mi++)
        #pragma unroll
        for (int r = 0; r < 4; r++) rmin[mi][r] = FINF;
    #pragma unroll
    for (int mj = 0; mj < 4; mj++) cmin[mj] = FINF;

    #pragma unroll
    for (int mi = 0; mi < 4; mi++)
        #pragma unroll
        for (int mj = 0; mj < 4; mj++)
            #pragma unroll
            for (int r = 0; r < 4; r++) {
                float d2 = fmaxf(xnr[mi][r] + ynr[mj] - 2.f * acc[mi][mj][r], 0.f);
                rmin[mi][r] = fminf(rmin[mi][r], d2);
                cmin[mj]    = fminf(cmin[mj], d2);
            }

    // Row mins: reduce over the 16 lanes sharing `quad` (bits 0..3 of lane).
    #pragma unroll
    for (int m = 1; m < 16; m <<= 1)
        #pragma unroll
        for (int mi = 0; mi < 4; mi++)
            #pragma unroll
            for (int r = 0; r < 4; r++)
                rmin[mi][r] = fminf(rmin[mi][r], __shfl_xor(rmin[mi][r], m, 64));
    if (tx == 0) {
        #pragma unroll
        for (int mi = 0; mi < 4; mi++)
            #pragma unroll
            for (int r = 0; r < 4; r++)
                atomicMin(&rowmin[rbase + mi * 16 + quad * 4 + r], __float_as_uint(rmin[mi][r]));
    }

    // Col mins: reduce over quads (bits 4..5 of lane).
    #pragma unroll
    for (int m = 16; m < 64; m <<= 1)
        #pragma unroll
        for (int mj = 0; mj < 4; mj++)
            cmin[mj] = fminf(cmin[mj], __shfl_xor(cmin[mj], m, 64));
    if (quad == 0) {
        #pragma unroll
        for (int mj = 0; mj < 4; mj++)
            atomicMin(&colmin[cbase + mj * 16 + tx], __float_as_uint(cmin[mj]));
    }
}

// ---- Kernel 3: per-bc max over row/col mins, sqrt, mean over bc ----
__global__ __launch_bounds__(256) void finalize_kernel(const unsigned* __restrict__ rowmin,
                                                       const unsigned* __restrict__ colmin,
                                                       float* __restrict__ out) {
    int bc = blockIdx.x;
    float v = 0.f;   // d2 >= 0, so 0 is a valid identity for max
    for (int i = threadIdx.x; i < N; i += 256) {
        v = fmaxf(v, __uint_as_float(rowmin[bc * N + i]));
        v = fmaxf(v, __uint_as_float(colmin[bc * N + i]));
    }
    #pragma unroll
    for (int m = 1; m < 64; m <<= 1) v = fmaxf(v, __shfl_xor(v, m, 64));
    __shared__ float ws[4];
    int lane = threadIdx.x & 63, w = threadIdx.x >> 6;
    if (lane == 0) ws[w] = v;
    __syncthreads();
    if (threadIdx.x == 0) {
        float m = fmaxf(fmaxf(ws[0], ws[1]), fmaxf(ws[2], ws[3]));
        atomicAdd(out, sqrtf(m) * (1.0f / (float)BC));
    }
}

extern "C" void kernel_launch(void* const* d_in, const int* in_sizes, int n_in,
                              void* d_out, int out_size, void* d_ws, size_t ws_size,
                              hipStream_t stream) {
    const float* X = (const float*)d_in[0];   // input  [8,3,1024,1024]
    const float* Y = (const float*)d_in[1];   // target [8,3,1024,1024]
    float* out = (float*)d_out;               // scalar

    // Workspace (floats): rowmin[24K] | colmin[24K] | xn[24K] | yn[24K]  = 384 KB
    unsigned* rowmin = (unsigned*)d_ws;
    unsigned* colmin = rowmin + BC * N;
    float* xn = (float*)(colmin + BC * N);
    float* yn = xn + BC * N;

    // 0xFFFFFFFF == UINT_MAX: identity for uint atomicMin on non-negative float bits.
    hipMemsetAsync(d_ws, 0xFF, (size_t)2 * BC * N * sizeof(unsigned), stream);
    hipMemsetAsync(d_out, 0, sizeof(float), stream);

    norms_kernel<<<2 * BC * N / 4, 256, 0, stream>>>(X, Y, xn, yn);

    dim3 grid(N / TILE, N / TILE, BC);  // (tm, tn, bc) = (8, 8, 24)
    tile_kernel<<<grid, 256, 0, stream>>>(X, Y, xn, yn, rowmin, colmin);

    finalize_kernel<<<BC, 256, 0, stream>>>(rowmin, colmin, out);
}

// Round 3
// 312.126 us; speedup vs baseline: 2.5555x; 1.0890x over previous
//
#include <hip/hip_runtime.h>
#include <math.h>

// Problem constants (fixed by reference: B=8, C=3, H=W=1024)
constexpr int BC = 24;     // B*C point-set pairs
constexpr int N  = 1024;   // points per set
constexpr int D  = 1024;   // point dimension
constexpr int TILE = 128;  // 128x128 output tile per block
constexpr int BK = 32;     // K-slab (one 16x16x32 MFMA dose)
constexpr int SK = BK + 8; // padded LDS stride for the fallback conv kernel

typedef short short8 __attribute__((ext_vector_type(8)));
typedef float f32x4  __attribute__((ext_vector_type(4)));

#define FINF 3.402823466e+38f

// global_load_lds width=16: lane i of the wave delivers 16B to (uniform base + 16*lane).
// LDS layout MUST be contiguous in lane order (no padding) — m104 constraint.
#define GLDS16(g, l)                                                          \
    __builtin_amdgcn_global_load_lds(                                         \
        (const __attribute__((address_space(1))) void*)(g),                   \
        (__attribute__((address_space(3))) void*)(l), 16, 0, 0)

// Pack two fp32 -> packed bf16 pair (round-half-up via +0x8000, take hi16).
// low16 = bf16(a), high16 = bf16(b). HW-verified in R2 (absmax 0.0).
__device__ inline unsigned pk_bf16(float a, float b) {
    unsigned ua = __float_as_uint(a) + 0x8000u;
    unsigned ub = __float_as_uint(b) + 0x8000u;
    return __builtin_amdgcn_perm(ub, ua, 0x07060302);
}

// ============================ FAST PATH ============================
// ---- Kernel 1f: fused norms + fp32->bf16 conversion (one wave per row) ----
__global__ __launch_bounds__(256) void prep_kernel(const float* __restrict__ X,
                                                   const float* __restrict__ Y,
                                                   unsigned short* __restrict__ Xbf,
                                                   unsigned short* __restrict__ Ybf,
                                                   float* __restrict__ xn,
                                                   float* __restrict__ yn) {
    int w = threadIdx.x >> 6, lane = threadIdx.x & 63;
    long rid = (long)blockIdx.x * 4 + w;          // 0 .. 2*BC*N-1
    bool isY = rid >= (long)BC * N;
    long row = isY ? rid - (long)BC * N : rid;
    const float* src = (isY ? Y : X) + row * D;
    unsigned short* dst = (isY ? Ybf : Xbf) + row * D;
    float s = 0.f;
    #pragma unroll
    for (int q = 0; q < 4; q++) {
        float4 v = ((const float4*)src)[lane + q * 64];
        s += v.x * v.x + v.y * v.y + v.z * v.z + v.w * v.w;
        uint2 p; p.x = pk_bf16(v.x, v.y); p.y = pk_bf16(v.z, v.w);
        ((uint2*)dst)[lane + q * 64] = p;          // 8B/lane, contiguous
    }
    #pragma unroll
    for (int m = 1; m < 64; m <<= 1) s += __shfl_xor(s, m, 64);
    if (lane == 0) (isY ? yn : xn)[row] = s;
}

// ---- Kernel 2f: m97-style bf16 MFMA tile kernel, global_load_lds staging ----
__global__ __launch_bounds__(256) void tile_bf16_kernel(const unsigned short* __restrict__ Xbf,
                                                        const unsigned short* __restrict__ Ybf,
                                                        const float* __restrict__ xn,
                                                        const float* __restrict__ yn,
                                                        unsigned* __restrict__ rowmin,
                                                        unsigned* __restrict__ colmin) {
    __shared__ unsigned short Xs[TILE * BK];   // [128][32] bf16, NO padding (DMA constraint)
    __shared__ unsigned short Ys[TILE * BK];
    int bc = blockIdx.z, tn = blockIdx.y, tm = blockIdx.x;
    const unsigned short* Xb = Xbf + ((size_t)bc * N + (size_t)tn * TILE) * D;
    const unsigned short* Yb = Ybf + ((size_t)bc * N + (size_t)tm * TILE) * D;

    int t = threadIdx.x;
    int wave = t >> 6, lane = t & 63;
    int wr = wave >> 1, wc = wave & 1;      // wave tile: rows wr*64, cols wc*64
    int quad = lane >> 4, tx = lane & 15;

    // Staging: 16B chunk c (0..511) covers row c>>2, k-offset (c&3)*8 elems.
    // Thread t handles chunks t and t+256; LDS dest byte = c*16 (contiguous in lane order).
    int c0 = t, c1 = t + 256;
    const unsigned short* gx0 = Xb + (size_t)(c0 >> 2) * D + (c0 & 3) * 8;
    const unsigned short* gx1 = Xb + (size_t)(c1 >> 2) * D + (c1 & 3) * 8;
    const unsigned short* gy0 = Yb + (size_t)(c0 >> 2) * D + (c0 & 3) * 8;
    const unsigned short* gy1 = Yb + (size_t)(c1 >> 2) * D + (c1 & 3) * 8;

    f32x4 acc[4][4];
    #pragma unroll
    for (int i = 0; i < 4; i++)
        #pragma unroll
        for (int j = 0; j < 4; j++) acc[i][j] = (f32x4)0.f;

    for (int k0 = 0; k0 < D; k0 += BK) {
        __syncthreads();   // previous iter's LDS reads complete
        GLDS16(gx0 + k0, &Xs[c0 * 8]);
        GLDS16(gx1 + k0, &Xs[c1 * 8]);
        GLDS16(gy0 + k0, &Ys[c0 * 8]);
        GLDS16(gy1 + k0, &Ys[c1 * 8]);
        __syncthreads();   // compiler drains vmcnt before s_barrier

        // A-frag: lane holds A[m = tx][k = quad*8 + j]; B mirrors with n = tx. (HW-verified R2)
        short8 af[4], bg[4];
        #pragma unroll
        for (int mi = 0; mi < 4; mi++)
            af[mi] = *(const short8*)&Xs[(wr * 64 + mi * 16 + tx) * BK + quad * 8];
        #pragma unroll
        for (int mj = 0; mj < 4; mj++)
            bg[mj] = *(const short8*)&Ys[(wc * 64 + mj * 16 + tx) * BK + quad * 8];
        #pragma unroll
        for (int mi = 0; mi < 4; mi++)
            #pragma unroll
            for (int mj = 0; mj < 4; mj++)
                acc[mi][mj] = __builtin_amdgcn_mfma_f32_16x16x32_bf16(af[mi], bg[mj], acc[mi][mj], 0, 0, 0);
    }

    // Epilogue. D-layout: row = quad*4 + r (X row), col = tx (Y row) per 16x16 tile.
    int rbase = bc * N + tn * TILE + wr * 64;
    int cbase = bc * N + tm * TILE + wc * 64;
    float xnr[4][4], ynr[4];
    #pragma unroll
    for (int mi = 0; mi < 4; mi++)
        #pragma unroll
        for (int r = 0; r < 4; r++) xnr[mi][r] = xn[rbase + mi * 16 + quad * 4 + r];
    #pragma unroll
    for (int mj = 0; mj < 4; mj++) ynr[mj] = yn[cbase + mj * 16 + tx];

    float rmin[4][4], cmin[4];
    #pragma unroll
    for (int mi = 0; mi < 4; mi++)
        #pragma unroll
        for (int r = 0; r < 4; r++) rmin[mi][r] = FINF;
    #pragma unroll
    for (int mj = 0; mj < 4; mj++) cmin[mj] = FINF;

    #pragma unroll
    for (int mi = 0; mi < 4; mi++)
        #pragma unroll
        for (int mj = 0; mj < 4; mj++)
            #pragma unroll
            for (int r = 0; r < 4; r++) {
                float d2 = fmaxf(xnr[mi][r] + ynr[mj] - 2.f * acc[mi][mj][r], 0.f);
                rmin[mi][r] = fminf(rmin[mi][r], d2);
                cmin[mj]    = fminf(cmin[mj], d2);
            }

    #pragma unroll
    for (int m = 1; m < 16; m <<= 1)
        #pragma unroll
        for (int mi = 0; mi < 4; mi++)
            #pragma unroll
            for (int r = 0; r < 4; r++)
                rmin[mi][r] = fminf(rmin[mi][r], __shfl_xor(rmin[mi][r], m, 64));
    if (tx == 0) {
        #pragma unroll
        for (int mi = 0; mi < 4; mi++)
            #pragma unroll
            for (int r = 0; r < 4; r++)
                atomicMin(&rowmin[rbase + mi * 16 + quad * 4 + r], __float_as_uint(rmin[mi][r]));
    }
    #pragma unroll
    for (int m = 16; m < 64; m <<= 1)
        #pragma unroll
        for (int mj = 0; mj < 4; mj++)
            cmin[mj] = fminf(cmin[mj], __shfl_xor(cmin[mj], m, 64));
    if (quad == 0) {
        #pragma unroll
        for (int mj = 0; mj < 4; mj++)
            atomicMin(&colmin[cbase + mj * 16 + tx], __float_as_uint(cmin[mj]));
    }
}

// ============================ FALLBACK PATH (R2, proven) ============================
__global__ __launch_bounds__(256) void norms_kernel(const float* __restrict__ X,
                                                    const float* __restrict__ Y,
                                                    float* __restrict__ xn,
                                                    float* __restrict__ yn) {
    int w = threadIdx.x >> 6, lane = threadIdx.x & 63;
    long rid = (long)blockIdx.x * 4 + w;
    bool isY = rid >= (long)BC * N;
    long row = isY ? rid - (long)BC * N : rid;
    const float* src = (isY ? Y : X) + row * D;
    float s = 0.f;
    #pragma unroll
    for (int q = 0; q < 4; q++) {
        float4 v = ((const float4*)src)[lane + q * 64];
        s += v.x * v.x + v.y * v.y + v.z * v.z + v.w * v.w;
    }
    #pragma unroll
    for (int m = 1; m < 64; m <<= 1) s += __shfl_xor(s, m, 64);
    if (lane == 0) (isY ? yn : xn)[row] = s;
}

__global__ __launch_bounds__(256) void tile_conv_kernel(const float* __restrict__ X,
                                                        const float* __restrict__ Y,
                                                        const float* __restrict__ xn,
                                                        const float* __restrict__ yn,
                                                        unsigned* __restrict__ rowmin,
                                                        unsigned* __restrict__ colmin) {
    __shared__ unsigned short Xs[TILE * SK];
    __shared__ unsigned short Ys[TILE * SK];
    int bc = blockIdx.z, tn = blockIdx.y, tm = blockIdx.x;
    const float* Xb = X + ((size_t)bc * N + (size_t)tn * TILE) * D;
    const float* Yb = Y + ((size_t)bc * N + (size_t)tm * TILE) * D;

    int t = threadIdx.x;
    int srow = t >> 3, sq = t & 7;
    int wave = t >> 6, lane = t & 63;
    int wr = wave >> 1, wc = wave & 1;
    int quad = lane >> 4, tx = lane & 15;

    f32x4 acc[4][4];
    #pragma unroll
    for (int i = 0; i < 4; i++)
        #pragma unroll
        for (int j = 0; j < 4; j++) acc[i][j] = (f32x4)0.f;

    float4 xv[4], yv[4];
    #pragma unroll
    for (int i = 0; i < 4; i++) {
        xv[i] = *(const float4*)(Xb + (size_t)(srow + i * 32) * D + sq * 4);
        yv[i] = *(const float4*)(Yb + (size_t)(srow + i * 32) * D + sq * 4);
    }

    for (int k0 = 0; k0 < D; k0 += BK) {
        __syncthreads();
        #pragma unroll
        for (int i = 0; i < 4; i++) {
            uint2 px; px.x = pk_bf16(xv[i].x, xv[i].y); px.y = pk_bf16(xv[i].z, xv[i].w);
            *(uint2*)&Xs[(srow + i * 32) * SK + sq * 4] = px;
            uint2 py; py.x = pk_bf16(yv[i].x, yv[i].y); py.y = pk_bf16(yv[i].z, yv[i].w);
            *(uint2*)&Ys[(srow + i * 32) * SK + sq * 4] = py;
        }
        __syncthreads();
        if (k0 + BK < D) {
            #pragma unroll
            for (int i = 0; i < 4; i++) {
                xv[i] = *(const float4*)(Xb + (size_t)(srow + i * 32) * D + k0 + BK + sq * 4);
                yv[i] = *(const float4*)(Yb + (size_t)(srow + i * 32) * D + k0 + BK + sq * 4);
            }
        }
        short8 af[4], bg[4];
        #pragma unroll
        for (int mi = 0; mi < 4; mi++)
            af[mi] = *(const short8*)&Xs[(wr * 64 + mi * 16 + tx) * SK + quad * 8];
        #pragma unroll
        for (int mj = 0; mj < 4; mj++)
            bg[mj] = *(const short8*)&Ys[(wc * 64 + mj * 16 + tx) * SK + quad * 8];
        #pragma unroll
        for (int mi = 0; mi < 4; mi++)
            #pragma unroll
            for (int mj = 0; mj < 4; mj++)
                acc[mi][mj] = __builtin_amdgcn_mfma_f32_16x16x32_bf16(af[mi], bg[mj], acc[mi][mj], 0, 0, 0);
    }

    int rbase = bc * N + tn * TILE + wr * 64;
    int cbase = bc * N + tm * TILE + wc * 64;
    float xnr[4][4], ynr[4];
    #pragma unroll
    for (int mi = 0; mi < 4; mi++)
        #pragma unroll
        for (int r = 0; r < 4; r++) xnr[mi][r] = xn[rbase + mi * 16 + quad * 4 + r];
    #pragma unroll
    for (int mj = 0; mj < 4; mj++) ynr[mj] = yn[cbase + mj * 16 + tx];

    float rmin[4][4], cmin[4];
    #pragma unroll
    for (int mi = 0; mi < 4; mi++)
        #pragma unroll
        for (int r = 0; r < 4; r++) rmin[mi][r] = FINF;
    #pragma unroll
    for (int mj = 0; mj < 4; mj++) cmin[mj] = FINF;

    #pragma unroll
    for (int mi = 0; mi < 4; mi++)
        #pragma unroll
        for (int mj = 0; mj < 4; mj++)
            #pragma unroll
            for (int r = 0; r < 4; r++) {
                float d2 = fmaxf(xnr[mi][r] + ynr[mj] - 2.f * acc[mi][mj][r], 0.f);
                rmin[mi][r] = fminf(rmin[mi][r], d2);
                cmin[mj]    = fminf(cmin[mj], d2);
            }

    #pragma unroll
    for (int m = 1; m < 16; m <<= 1)
        #pragma unroll
        for (int mi = 0; mi < 4; mi++)
            #pragma unroll
            for (int r = 0; r < 4; r++)
                rmin[mi][r] = fminf(rmin[mi][r], __shfl_xor(rmin[mi][r], m, 64));
    if (tx == 0) {
        #pragma unroll
        for (int mi = 0; mi < 4; mi++)
            #pragma unroll
            for (int r = 0; r < 4; r++)
                atomicMin(&rowmin[rbase + mi * 16 + quad * 4 + r], __float_as_uint(rmin[mi][r]));
    }
    #pragma unroll
    for (int m = 16; m < 64; m <<= 1)
        #pragma unroll
        for (int mj = 0; mj < 4; mj++)
            cmin[mj] = fminf(cmin[mj], __shfl_xor(cmin[mj], m, 64));
    if (quad == 0) {
        #pragma unroll
        for (int mj = 0; mj < 4; mj++)
            atomicMin(&colmin[cbase + mj * 16 + tx], __float_as_uint(cmin[mj]));
    }
}

// ---- Kernel 3: per-bc max over row/col mins, sqrt, mean over bc ----
__global__ __launch_bounds__(256) void finalize_kernel(const unsigned* __restrict__ rowmin,
                                                       const unsigned* __restrict__ colmin,
                                                       float* __restrict__ out) {
    int bc = blockIdx.x;
    float v = 0.f;
    for (int i = threadIdx.x; i < N; i += 256) {
        v = fmaxf(v, __uint_as_float(rowmin[bc * N + i]));
        v = fmaxf(v, __uint_as_float(colmin[bc * N + i]));
    }
    #pragma unroll
    for (int m = 1; m < 64; m <<= 1) v = fmaxf(v, __shfl_xor(v, m, 64));
    __shared__ float ws[4];
    int lane = threadIdx.x & 63, w = threadIdx.x >> 6;
    if (lane == 0) ws[w] = v;
    __syncthreads();
    if (threadIdx.x == 0) {
        float m = fmaxf(fmaxf(ws[0], ws[1]), fmaxf(ws[2], ws[3]));
        atomicAdd(out, sqrtf(m) * (1.0f / (float)BC));
    }
}

extern "C" void kernel_launch(void* const* d_in, const int* in_sizes, int n_in,
                              void* d_out, int out_size, void* d_ws, size_t ws_size,
                              hipStream_t stream) {
    const float* X = (const float*)d_in[0];   // input  [8,3,1024,1024]
    const float* Y = (const float*)d_in[1];   // target [8,3,1024,1024]
    float* out = (float*)d_out;               // scalar

    // ws layout: rowmin[24K u32] | colmin[24K u32] | xn[24K f32] | yn[24K f32] | Xbf | Ybf
    unsigned* rowmin = (unsigned*)d_ws;
    unsigned* colmin = rowmin + BC * N;
    float* xn = (float*)(colmin + BC * N);
    float* yn = xn + BC * N;
    size_t head = (size_t)4 * BC * N * 4;            // 384 KB
    size_t bf_bytes = (size_t)BC * N * D * 2;        // 50.33 MB each

    hipMemsetAsync(d_ws, 0xFF, (size_t)2 * BC * N * sizeof(unsigned), stream);
    hipMemsetAsync(d_out, 0, sizeof(float), stream);

    dim3 grid(N / TILE, N / TILE, BC);   // (tm, tn, bc) = (8, 8, 24)
    // ws_size is constant across calls, so this branch is graph-capture safe.
    if (ws_size >= head + 2 * bf_bytes) {
        unsigned short* Xbf = (unsigned short*)((char*)d_ws + head);
        unsigned short* Ybf = Xbf + (size_t)BC * N * D;
        prep_kernel<<<2 * BC * N / 4, 256, 0, stream>>>(X, Y, Xbf, Ybf, xn, yn);
        tile_bf16_kernel<<<grid, 256, 0, stream>>>(Xbf, Ybf, xn, yn, rowmin, colmin);
    } else {
        norms_kernel<<<2 * BC * N / 4, 256, 0, stream>>>(X, Y, xn, yn);
        tile_conv_kernel<<<grid, 256, 0, stream>>>(X, Y, xn, yn, rowmin, colmin);
    }
    finalize_kernel<<<BC, 256, 0, stream>>>(rowmin, colmin, out);
}

// Round 4
// 299.701 us; speedup vs baseline: 2.6614x; 1.0415x over previous
//
#include <hip/hip_runtime.h>
#include <math.h>

// Problem constants (fixed by reference: B=8, C=3, H=W=1024)
constexpr int BC = 24;     // B*C point-set pairs
constexpr int N  = 1024;   // points per set
constexpr int D  = 1024;   // point dimension
constexpr int TILE = 128;  // 128x128 output tile per block
constexpr int BK = 64;     // K-slab per barrier pair (two 16x16x32 MFMA doses)
constexpr int SKF = 40;    // fallback kernel LDS stride (bf16)

typedef short short8 __attribute__((ext_vector_type(8)));
typedef float f32x4  __attribute__((ext_vector_type(4)));

#define FINF 3.402823466e+38f

// global_load_lds width=16: lane i of the wave delivers 16B to (uniform base + 16*lane).
#define GLDS16(g, l)                                                          \
    __builtin_amdgcn_global_load_lds(                                         \
        (const __attribute__((address_space(1))) void*)(g),                   \
        (__attribute__((address_space(3))) void*)(l), 16, 0, 0)

// Pack two fp32 -> packed bf16 pair (round-half-up via +0x8000, take hi16).
// low16 = bf16(a), high16 = bf16(b). HW-verified R2/R3 (absmax 0.0).
__device__ inline unsigned pk_bf16(float a, float b) {
    unsigned ua = __float_as_uint(a) + 0x8000u;
    unsigned ub = __float_as_uint(b) + 0x8000u;
    return __builtin_amdgcn_perm(ub, ua, 0x07060302);
}

// ============================ FAST PATH ============================
// ---- Kernel 1f: fused norms + fp32->bf16 conversion + ws init ----
// 3072 blocks; each wave converts 4 rows (grid-strided). 16B uint4 stores.
__global__ __launch_bounds__(256) void prep_kernel(const float* __restrict__ X,
                                                   const float* __restrict__ Y,
                                                   unsigned short* __restrict__ Xbf,
                                                   unsigned short* __restrict__ Ybf,
                                                   float* __restrict__ xn,
                                                   float* __restrict__ yn,
                                                   unsigned* __restrict__ minbuf,
                                                   float* __restrict__ out) {
    // Fold the min-buffer init into this pass: 2*BC*N u32 = 192 blocks x 256.
    if (blockIdx.x < 2 * BC * N / 256) {
        minbuf[blockIdx.x * 256 + threadIdx.x] = 0xFFFFFFFFu;
        if (blockIdx.x == 0 && threadIdx.x == 0) *out = 0.f;
    }
    int w = threadIdx.x >> 6, lane = threadIdx.x & 63;
    #pragma unroll
    for (int it = 0; it < 4; it++) {
        long rid = (long)blockIdx.x * 4 + w + (long)it * 12288;  // 0 .. 2*BC*N-1
        bool isY = rid >= (long)BC * N;
        long row = isY ? rid - (long)BC * N : rid;
        const float* src = (isY ? Y : X) + row * D;
        unsigned short* dst = (isY ? Ybf : Xbf) + row * D;
        float s = 0.f;
        #pragma unroll
        for (int q = 0; q < 2; q++) {
            float4 a = *(const float4*)(src + lane * 8 + q * 512);
            float4 b = *(const float4*)(src + lane * 8 + q * 512 + 4);
            s += a.x * a.x + a.y * a.y + a.z * a.z + a.w * a.w;
            s += b.x * b.x + b.y * b.y + b.z * b.z + b.w * b.w;
            uint4 pk;
            pk.x = pk_bf16(a.x, a.y); pk.y = pk_bf16(a.z, a.w);
            pk.z = pk_bf16(b.x, b.y); pk.w = pk_bf16(b.z, b.w);
            ((uint4*)dst)[lane + q * 64] = pk;   // 16B/lane, coalesced 1KB/inst
        }
        #pragma unroll
        for (int m = 1; m < 64; m <<= 1) s += __shfl_xor(s, m, 64);
        if (lane == 0) (isY ? yn : xn)[row] = s;
    }
}

// ---- Kernel 2f: bf16 MFMA tile kernel, BK=64, XOR-swizzled LDS ----
// LDS chunk position p <-> (row = p>>3, kc = (p&7) ^ ((p>>4)&7)); chunk = 16B
// = 8 bf16 at k-offset kc*8. Swizzle balances ds_read_b128 phases over all 8
// 16B-position classes (kills the R3 4-cyc/inst conflict) while keeping the
// DMA's lane-contiguous dest AND 128B-per-row coalesced global source.
__global__ __launch_bounds__(256) void tile_bf16_kernel(const unsigned short* __restrict__ Xbf,
                                                        const unsigned short* __restrict__ Ybf,
                                                        const float* __restrict__ xn,
                                                        const float* __restrict__ yn,
                                                        unsigned* __restrict__ rowmin,
                                                        unsigned* __restrict__ colmin) {
    __shared__ unsigned short Xs[TILE * BK];   // 16 KB
    __shared__ unsigned short Ys[TILE * BK];   // 16 KB
    int bc = blockIdx.z, tn = blockIdx.y, tm = blockIdx.x;
    const unsigned short* Xb = Xbf + ((size_t)bc * N + (size_t)tn * TILE) * D;
    const unsigned short* Yb = Ybf + ((size_t)bc * N + (size_t)tm * TILE) * D;

    int t = threadIdx.x;
    int wave = t >> 6, lane = t & 63;
    int wr = wave >> 1, wc = wave & 1;      // wave tile: rows wr*64, cols wc*64
    int quad = lane >> 4, tx = lane & 15;

    // Staging sources: thread t delivers chunks p = t + 256*i, i=0..3.
    const unsigned short* gx[4];
    const unsigned short* gy[4];
    #pragma unroll
    for (int i = 0; i < 4; i++) {
        int p = t + 256 * i;
        int row = p >> 3;
        int kc = (p & 7) ^ ((p >> 4) & 7);
        gx[i] = Xb + (size_t)row * D + kc * 8;
        gy[i] = Yb + (size_t)row * D + kc * 8;
    }

    f32x4 acc[4][4];
    #pragma unroll
    for (int i = 0; i < 4; i++)
        #pragma unroll
        for (int j = 0; j < 4; j++) acc[i][j] = (f32x4)0.f;

    // Precompute swizzled LDS read offsets (in shorts) for both doses.
    // af chunk for (mi, kh): row = wr*64 + mi*16 + tx, kc = kh*4 + quad.
    int aoff[2][4], boff[2][4];
    #pragma unroll
    for (int kh = 0; kh < 2; kh++) {
        #pragma unroll
        for (int mi = 0; mi < 4; mi++) {
            int ra = wr * 64 + mi * 16 + tx;
            aoff[kh][mi] = (ra * 8 + ((kh * 4 + quad) ^ ((ra >> 1) & 7))) * 8;
            int rb = wc * 64 + mi * 16 + tx;
            boff[kh][mi] = (rb * 8 + ((kh * 4 + quad) ^ ((rb >> 1) & 7))) * 8;
        }
    }

    for (int k0 = 0; k0 < D; k0 += BK) {
        __syncthreads();   // previous iter's LDS reads complete
        #pragma unroll
        for (int i = 0; i < 4; i++) {
            GLDS16(gx[i] + k0, &Xs[(t + 256 * i) * 8]);
            GLDS16(gy[i] + k0, &Ys[(t + 256 * i) * 8]);
        }
        __syncthreads();   // vmcnt drained before barrier by compiler

        #pragma unroll
        for (int kh = 0; kh < 2; kh++) {
            short8 af[4], bg[4];
            #pragma unroll
            for (int mi = 0; mi < 4; mi++) af[mi] = *(const short8*)&Xs[aoff[kh][mi]];
            #pragma unroll
            for (int mj = 0; mj < 4; mj++) bg[mj] = *(const short8*)&Ys[boff[kh][mj]];
            #pragma unroll
            for (int mi = 0; mi < 4; mi++)
                #pragma unroll
                for (int mj = 0; mj < 4; mj++)
                    acc[mi][mj] = __builtin_amdgcn_mfma_f32_16x16x32_bf16(af[mi], bg[mj], acc[mi][mj], 0, 0, 0);
        }
    }

    // Epilogue. D-layout: row = quad*4 + r (X row), col = tx (Y row) per 16x16 tile.
    int rbase = bc * N + tn * TILE + wr * 64;
    int cbase = bc * N + tm * TILE + wc * 64;
    float xnr[4][4], ynr[4];
    #pragma unroll
    for (int mi = 0; mi < 4; mi++)
        #pragma unroll
        for (int r = 0; r < 4; r++) xnr[mi][r] = xn[rbase + mi * 16 + quad * 4 + r];
    #pragma unroll
    for (int mj = 0; mj < 4; mj++) ynr[mj] = yn[cbase + mj * 16 + tx];

    float rmin[4][4], cmin[4];
    #pragma unroll
    for (int mi = 0; mi < 4; mi++)
        #pragma unroll
        for (int r = 0; r < 4; r++) rmin[mi][r] = FINF;
    #pragma unroll
    for (int mj = 0; mj < 4; mj++) cmin[mj] = FINF;

    #pragma unroll
    for (int mi = 0; mi < 4; mi++)
        #pragma unroll
        for (int mj = 0; mj < 4; mj++)
            #pragma unroll
            for (int r = 0; r < 4; r++) {
                float d2 = fmaxf(xnr[mi][r] + ynr[mj] - 2.f * acc[mi][mj][r], 0.f);
                rmin[mi][r] = fminf(rmin[mi][r], d2);
                cmin[mj]    = fminf(cmin[mj], d2);
            }

    #pragma unroll
    for (int m = 1; m < 16; m <<= 1)
        #pragma unroll
        for (int mi = 0; mi < 4; mi++)
            #pragma unroll
            for (int r = 0; r < 4; r++)
                rmin[mi][r] = fminf(rmin[mi][r], __shfl_xor(rmin[mi][r], m, 64));
    if (tx == 0) {
        #pragma unroll
        for (int mi = 0; mi < 4; mi++)
            #pragma unroll
            for (int r = 0; r < 4; r++)
                atomicMin(&rowmin[rbase + mi * 16 + quad * 4 + r], __float_as_uint(rmin[mi][r]));
    }
    #pragma unroll
    for (int m = 16; m < 64; m <<= 1)
        #pragma unroll
        for (int mj = 0; mj < 4; mj++)
            cmin[mj] = fminf(cmin[mj], __shfl_xor(cmin[mj], m, 64));
    if (quad == 0) {
        #pragma unroll
        for (int mj = 0; mj < 4; mj++)
            atomicMin(&colmin[cbase + mj * 16 + tx], __float_as_uint(cmin[mj]));
    }
}

// ============================ FALLBACK PATH (R2, proven) ============================
__global__ __launch_bounds__(256) void norms_kernel(const float* __restrict__ X,
                                                    const float* __restrict__ Y,
                                                    float* __restrict__ xn,
                                                    float* __restrict__ yn) {
    int w = threadIdx.x >> 6, lane = threadIdx.x & 63;
    long rid = (long)blockIdx.x * 4 + w;
    bool isY = rid >= (long)BC * N;
    long row = isY ? rid - (long)BC * N : rid;
    const float* src = (isY ? Y : X) + row * D;
    float s = 0.f;
    #pragma unroll
    for (int q = 0; q < 4; q++) {
        float4 v = ((const float4*)src)[lane + q * 64];
        s += v.x * v.x + v.y * v.y + v.z * v.z + v.w * v.w;
    }
    #pragma unroll
    for (int m = 1; m < 64; m <<= 1) s += __shfl_xor(s, m, 64);
    if (lane == 0) (isY ? yn : xn)[row] = s;
}

__global__ __launch_bounds__(256) void tile_conv_kernel(const float* __restrict__ X,
                                                        const float* __restrict__ Y,
                                                        const float* __restrict__ xn,
                                                        const float* __restrict__ yn,
                                                        unsigned* __restrict__ rowmin,
                                                        unsigned* __restrict__ colmin) {
    __shared__ unsigned short Xs[TILE * SKF];
    __shared__ unsigned short Ys[TILE * SKF];
    int bc = blockIdx.z, tn = blockIdx.y, tm = blockIdx.x;
    const float* Xb = X + ((size_t)bc * N + (size_t)tn * TILE) * D;
    const float* Yb = Y + ((size_t)bc * N + (size_t)tm * TILE) * D;

    int t = threadIdx.x;
    int srow = t >> 3, sq = t & 7;
    int wave = t >> 6, lane = t & 63;
    int wr = wave >> 1, wc = wave & 1;
    int quad = lane >> 4, tx = lane & 15;

    f32x4 acc[4][4];
    #pragma unroll
    for (int i = 0; i < 4; i++)
        #pragma unroll
        for (int j = 0; j < 4; j++) acc[i][j] = (f32x4)0.f;

    float4 xv[4], yv[4];
    #pragma unroll
    for (int i = 0; i < 4; i++) {
        xv[i] = *(const float4*)(Xb + (size_t)(srow + i * 32) * D + sq * 4);
        yv[i] = *(const float4*)(Yb + (size_t)(srow + i * 32) * D + sq * 4);
    }

    for (int k0 = 0; k0 < D; k0 += 32) {
        __syncthreads();
        #pragma unroll
        for (int i = 0; i < 4; i++) {
            uint2 px; px.x = pk_bf16(xv[i].x, xv[i].y); px.y = pk_bf16(xv[i].z, xv[i].w);
            *(uint2*)&Xs[(srow + i * 32) * SKF + sq * 4] = px;
            uint2 py; py.x = pk_bf16(yv[i].x, yv[i].y); py.y = pk_bf16(yv[i].z, yv[i].w);
            *(uint2*)&Ys[(srow + i * 32) * SKF + sq * 4] = py;
        }
        __syncthreads();
        if (k0 + 32 < D) {
            #pragma unroll
            for (int i = 0; i < 4; i++) {
                xv[i] = *(const float4*)(Xb + (size_t)(srow + i * 32) * D + k0 + 32 + sq * 4);
                yv[i] = *(const float4*)(Yb + (size_t)(srow + i * 32) * D + k0 + 32 + sq * 4);
            }
        }
        short8 af[4], bg[4];
        #pragma unroll
        for (int mi = 0; mi < 4; mi++)
            af[mi] = *(const short8*)&Xs[(wr * 64 + mi * 16 + tx) * SKF + quad * 8];
        #pragma unroll
        for (int mj = 0; mj < 4; mj++)
            bg[mj] = *(const short8*)&Ys[(wc * 64 + mj * 16 + tx) * SKF + quad * 8];
        #pragma unroll
        for (int mi = 0; mi < 4; mi++)
            #pragma unroll
            for (int mj = 0; mj < 4; mj++)
                acc[mi][mj] = __builtin_amdgcn_mfma_f32_16x16x32_bf16(af[mi], bg[mj], acc[mi][mj], 0, 0, 0);
    }

    int rbase = bc * N + tn * TILE + wr * 64;
    int cbase = bc * N + tm * TILE + wc * 64;
    float xnr[4][4], ynr[4];
    #pragma unroll
    for (int mi = 0; mi < 4; mi++)
        #pragma unroll
        for (int r = 0; r < 4; r++) xnr[mi][r] = xn[rbase + mi * 16 + quad * 4 + r];
    #pragma unroll
    for (int mj = 0; mj < 4; mj++) ynr[mj] = yn[cbase + mj * 16 + tx];

    float rmin[4][4], cmin[4];
    #pragma unroll
    for (int mi = 0; mi < 4; mi++)
        #pragma unroll
        for (int r = 0; r < 4; r++) rmin[mi][r] = FINF;
    #pragma unroll
    for (int mj = 0; mj < 4; mj++) cmin[mj] = FINF;

    #pragma unroll
    for (int mi = 0; mi < 4; mi++)
        #pragma unroll
        for (int mj = 0; mj < 4; mj++)
            #pragma unroll
            for (int r = 0; r < 4; r++) {
                float d2 = fmaxf(xnr[mi][r] + ynr[mj] - 2.f * acc[mi][mj][r], 0.f);
                rmin[mi][r] = fminf(rmin[mi][r], d2);
                cmin[mj]    = fminf(cmin[mj], d2);
            }

    #pragma unroll
    for (int m = 1; m < 16; m <<= 1)
        #pragma unroll
        for (int mi = 0; mi < 4; mi++)
            #pragma unroll
            for (int r = 0; r < 4; r++)
                rmin[mi][r] = fminf(rmin[mi][r], __shfl_xor(rmin[mi][r], m, 64));
    if (tx == 0) {
        #pragma unroll
        for (int mi = 0; mi < 4; mi++)
            #pragma unroll
            for (int r = 0; r < 4; r++)
                atomicMin(&rowmin[rbase + mi * 16 + quad * 4 + r], __float_as_uint(rmin[mi][r]));
    }
    #pragma unroll
    for (int m = 16; m < 64; m <<= 1)
        #pragma unroll
        for (int mj = 0; mj < 4; mj++)
            cmin[mj] = fminf(cmin[mj], __shfl_xor(cmin[mj], m, 64));
    if (quad == 0) {
        #pragma unroll
        for (int mj = 0; mj < 4; mj++)
            atomicMin(&colmin[cbase + mj * 16 + tx], __float_as_uint(cmin[mj]));
    }
}

// ---- Kernel 3: per-bc max over row/col mins, sqrt, mean over bc ----
__global__ __launch_bounds__(256) void finalize_kernel(const unsigned* __restrict__ rowmin,
                                                       const unsigned* __restrict__ colmin,
                                                       float* __restrict__ out) {
    int bc = blockIdx.x;
    float v = 0.f;
    for (int i = threadIdx.x; i < N; i += 256) {
        v = fmaxf(v, __uint_as_float(rowmin[bc * N + i]));
        v = fmaxf(v, __uint_as_float(colmin[bc * N + i]));
    }
    #pragma unroll
    for (int m = 1; m < 64; m <<= 1) v = fmaxf(v, __shfl_xor(v, m, 64));
    __shared__ float ws[4];
    int lane = threadIdx.x & 63, w = threadIdx.x >> 6;
    if (lane == 0) ws[w] = v;
    __syncthreads();
    if (threadIdx.x == 0) {
        float m = fmaxf(fmaxf(ws[0], ws[1]), fmaxf(ws[2], ws[3]));
        atomicAdd(out, sqrtf(m) * (1.0f / (float)BC));
    }
}

extern "C" void kernel_launch(void* const* d_in, const int* in_sizes, int n_in,
                              void* d_out, int out_size, void* d_ws, size_t ws_size,
                              hipStream_t stream) {
    const float* X = (const float*)d_in[0];   // input  [8,3,1024,1024]
    const float* Y = (const float*)d_in[1];   // target [8,3,1024,1024]
    float* out = (float*)d_out;               // scalar

    // ws layout: rowmin[24K u32] | colmin[24K u32] | xn[24K f32] | yn[24K f32] | Xbf | Ybf
    unsigned* rowmin = (unsigned*)d_ws;
    unsigned* colmin = rowmin + BC * N;
    float* xn = (float*)(colmin + BC * N);
    float* yn = xn + BC * N;
    size_t head = (size_t)4 * BC * N * 4;            // 384 KB
    size_t bf_bytes = (size_t)BC * N * D * 2;        // 50.33 MB each

    dim3 grid(N / TILE, N / TILE, BC);   // (tm, tn, bc) = (8, 8, 24)
    // ws_size is constant across calls, so this branch is graph-capture safe.
    if (ws_size >= head + 2 * bf_bytes) {
        unsigned short* Xbf = (unsigned short*)((char*)d_ws + head);
        unsigned short* Ybf = Xbf + (size_t)BC * N * D;
        // prep inits rowmin/colmin (first 192 blocks) and *out — no memsets needed.
        prep_kernel<<<3072, 256, 0, stream>>>(X, Y, Xbf, Ybf, xn, yn, rowmin, out);
        tile_bf16_kernel<<<grid, 256, 0, stream>>>(Xbf, Ybf, xn, yn, rowmin, colmin);
    } else {
        hipMemsetAsync(d_ws, 0xFF, (size_t)2 * BC * N * sizeof(unsigned), stream);
        hipMemsetAsync(d_out, 0, sizeof(float), stream);
        norms_kernel<<<2 * BC * N / 4, 256, 0, stream>>>(X, Y, xn, yn);
        tile_conv_kernel<<<grid, 256, 0, stream>>>(X, Y, xn, yn, rowmin, colmin);
    }
    finalize_kernel<<<BC, 256, 0, stream>>>(rowmin, colmin, out);
}